// Round 2
// baseline (3675.652 us; speedup 1.0000x reference)
//
#include <hip/hip_runtime.h>
#include <hip/hip_bf16.h>

#define NB 8
#define NC 256
#define NH_ 8
#define NL_ 4
#define NP_ 4
#define NLAYERS_ 6
#define FFN_ 1024
#define Q_ 5440
#define DH_ 32
#define M_ (NB*Q_)        // 43520
#define MCH (M_/4)        // 10880  (FFN chunk rows)

typedef __attribute__((ext_vector_type(8))) short bf16x8;
typedef __attribute__((ext_vector_type(4))) short bf16x4;
typedef __attribute__((ext_vector_type(4))) float f32x4;

__device__ __forceinline__ unsigned short f2bf(float f) {
  unsigned int u = __float_as_uint(f);
  u += 0x7fffu + ((u >> 16) & 1u);
  return (unsigned short)(u >> 16);
}
__device__ __forceinline__ float bf2f(unsigned short s) {
  return __uint_as_float(((unsigned int)s) << 16);
}

// ---------------- prep kernels ----------------
// W: [L][Kd][Nd] fp32  ->  Wt rows at [l][nOff+n][k] within [L][NdTot][Kd] bf16
__global__ void transpose_w2_k(const float* __restrict__ W, unsigned short* __restrict__ Wt,
                               int L, int Kd, int Nd, int NdTot, int nOff) {
  size_t total = (size_t)L * Nd * Kd;
  for (size_t i = (size_t)blockIdx.x * blockDim.x + threadIdx.x; i < total;
       i += (size_t)gridDim.x * blockDim.x) {
    int k = (int)(i % Kd);
    size_t r = i / Kd;
    int n = (int)(r % Nd);
    int l = (int)(r / Nd);
    Wt[((size_t)l * NdTot + nOff + n) * Kd + k] = f2bf(W[((size_t)l * Kd + k) * Nd + n]);
  }
}

__global__ void bias_cat_k(const float* __restrict__ bs, const float* __restrict__ ba,
                           float* __restrict__ bsa) {
  int i = blockIdx.x * blockDim.x + threadIdx.x;
  if (i >= NLAYERS_ * 384) return;
  int l = i / 384, n = i % 384;
  bsa[i] = (n < 256) ? bs[l * 256 + n] : ba[l * 128 + (n - 256)];
}

// ---------------- GEMM: Y[M,N] = X[M,K] @ Wt[N,K]^T + bias ----------------
// 64x64 tile, BK=32, 4 waves each 32x32 (2x2 frags of 16x16x32 MFMA)
#define LDSS 40  // 32 + 8 pad (2-way bank aliasing only -> free)

template <bool IN_BF16, bool ADD_POS, bool RELU, bool OUT_BF16>
__global__ __launch_bounds__(256)
void gemm_k(const void* __restrict__ Xv, const float* __restrict__ Pf,
            const float* __restrict__ Le,
            const unsigned short* __restrict__ Wt, const float* __restrict__ bias,
            void* __restrict__ Yv, int Kdim, int Ndim) {
  __shared__ unsigned short Alds[64 * LDSS];
  __shared__ unsigned short Blds[64 * LDSS];
  const int t = threadIdx.x;
  const int n0 = blockIdx.x * 64;
  const int m0 = blockIdx.y * 64;
  const int wave = t >> 6, lane = t & 63;
  const int wr = wave >> 1, wc = wave & 1;
  const int lr = lane & 15, lk = lane >> 4;
  const int r = t >> 3, c4 = t & 7;  // staging coords: 32 rows x 8 quads

  f32x4 acc[2][2];
#pragma unroll
  for (int i = 0; i < 2; ++i)
#pragma unroll
    for (int j = 0; j < 2; ++j)
#pragma unroll
      for (int e = 0; e < 4; ++e) acc[i][j][e] = 0.f;

  const float* Xf = (const float*)Xv;
  const unsigned short* Xb = (const unsigned short*)Xv;

  for (int kt = 0; kt < Kdim; kt += 32) {
#pragma unroll
    for (int p = 0; p < 2; ++p) {
      int row = p * 32 + r;
      // --- stage A (convert fp32->bf16, optional pos+level-embed add) ---
      if constexpr (!IN_BF16) {
        size_t gof = (size_t)(m0 + row) * Kdim + kt + c4 * 4;
        f32x4 v = *(const f32x4*)(Xf + gof);
        if constexpr (ADD_POS) {
          int q = (m0 + row) % Q_;
          int lvl = q < 4096 ? 0 : (q < 5120 ? 1 : (q < 5376 ? 2 : 3));
          f32x4 pv = *(const f32x4*)(Pf + gof);
          f32x4 ev = *(const f32x4*)(Le + lvl * NC + kt + c4 * 4);
          v = v + pv + ev;
        }
        bf16x4 sv;
        sv[0] = (short)f2bf(v[0]); sv[1] = (short)f2bf(v[1]);
        sv[2] = (short)f2bf(v[2]); sv[3] = (short)f2bf(v[3]);
        *(bf16x4*)&Alds[row * LDSS + c4 * 4] = sv;
      } else {
        size_t gof = (size_t)(m0 + row) * Kdim + kt + c4 * 4;
        *(bf16x4*)&Alds[row * LDSS + c4 * 4] = *(const bf16x4*)(Xb + gof);
      }
      // --- stage B from Wt[N][K] bf16 ---
      size_t wof = (size_t)(n0 + row) * Kdim + kt + c4 * 4;
      *(bf16x4*)&Blds[row * LDSS + c4 * 4] = *(const bf16x4*)(Wt + wof);
    }
    __syncthreads();

    bf16x8 a0 = *(const bf16x8*)&Alds[(wr * 32 + lr) * LDSS + lk * 8];
    bf16x8 a1 = *(const bf16x8*)&Alds[(wr * 32 + 16 + lr) * LDSS + lk * 8];
    bf16x8 b0 = *(const bf16x8*)&Blds[(wc * 32 + lr) * LDSS + lk * 8];
    bf16x8 b1 = *(const bf16x8*)&Blds[(wc * 32 + 16 + lr) * LDSS + lk * 8];
    acc[0][0] = __builtin_amdgcn_mfma_f32_16x16x32_bf16(a0, b0, acc[0][0], 0, 0, 0);
    acc[0][1] = __builtin_amdgcn_mfma_f32_16x16x32_bf16(a0, b1, acc[0][1], 0, 0, 0);
    acc[1][0] = __builtin_amdgcn_mfma_f32_16x16x32_bf16(a1, b0, acc[1][0], 0, 0, 0);
    acc[1][1] = __builtin_amdgcn_mfma_f32_16x16x32_bf16(a1, b1, acc[1][1], 0, 0, 0);
    __syncthreads();
  }

  // epilogue: C/D layout col=lane&15, row=(lane>>4)*4+reg  [HW-verified]
  const int orow = m0 + wr * 32;
  const int ocol = n0 + wc * 32;
#pragma unroll
  for (int fi = 0; fi < 2; ++fi)
#pragma unroll
    for (int fj = 0; fj < 2; ++fj) {
      int col = ocol + fj * 16 + lr;
      float bv = bias[col];
#pragma unroll
      for (int rr = 0; rr < 4; ++rr) {
        int row = orow + fi * 16 + lk * 4 + rr;
        float v = acc[fi][fj][rr] + bv;
        if constexpr (RELU) v = fmaxf(v, 0.f);
        if constexpr (OUT_BF16)
          ((unsigned short*)Yv)[(size_t)row * Ndim + col] = f2bf(v);
        else
          ((float*)Yv)[(size_t)row * Ndim + col] = v;
      }
    }
}

// ---------------- deformable sampling ----------------
// one wave per (b,q,h). sa row (bf16, stride 384): [0..255]=offsets
// (h*32 + s*2 + {x,y}), [256..383]=attn logits (h*16 + s), s = l*4+p.
__global__ __launch_bounds__(256)
void samp_k(const unsigned short* __restrict__ value, const unsigned short* __restrict__ sa,
            float* __restrict__ attn_feat) {
  int gw = blockIdx.x * 4 + (threadIdx.x >> 6);
  int lane = threadIdx.x & 63;
  int h = gw & 7;
  int bq = gw >> 3;  // 0..43519
  int q = bq % Q_;
  int b = bq / Q_;

  int lvl, rem;
  if (q < 4096)      { lvl = 0; rem = q; }
  else if (q < 5120) { lvl = 1; rem = q - 4096; }
  else if (q < 5376) { lvl = 2; rem = q - 5120; }
  else               { lvl = 3; rem = q - 5376; }
  int wq = 64 >> lvl;
  float inv = 1.0f / (float)wq;
  float refx = ((rem % wq) + 0.5f) * inv;
  float refy = ((rem / wq) + 0.5f) * inv;

  const unsigned short* sa_bq = sa + (size_t)bq * 384;

  // softmax over 16 samples (replicated across the four 16-lane groups)
  int s = lane & 15;
  float logit = bf2f(sa_bq[256 + h * 16 + s]);
  float mx = logit;
  mx = fmaxf(mx, __shfl_xor(mx, 1));
  mx = fmaxf(mx, __shfl_xor(mx, 2));
  mx = fmaxf(mx, __shfl_xor(mx, 4));
  mx = fmaxf(mx, __shfl_xor(mx, 8));
  float e = __expf(logit - mx);
  float sum = e;
  sum += __shfl_xor(sum, 1);
  sum += __shfl_xor(sum, 2);
  sum += __shfl_xor(sum, 4);
  sum += __shfl_xor(sum, 8);
  float aw = e / sum;

  // per-sample math (sample = lane&15)
  float ox = bf2f(sa_bq[h * 32 + s * 2 + 0]);
  float oy = bf2f(sa_bq[h * 32 + s * 2 + 1]);
  int sl = s >> 2;
  int sw = 64 >> sl;
  int sstart = (sl == 0) ? 0 : (sl == 1) ? 4096 : (sl == 2) ? 5120 : 5376;
  float x = fmaf(refx, (float)sw, ox) - 0.5f;
  float y = fmaf(refy, (float)sw, oy) - 0.5f;
  float x0f = floorf(x), y0f = floorf(y);
  float fx = x - x0f, fy = y - y0f;
  int x0 = (int)x0f, y0 = (int)y0f;
  float w[4];
  int a[4];
  int base_bh = ((b * Q_ + sstart) * NH_ + h) * DH_;
#pragma unroll
  for (int c = 0; c < 4; ++c) {
    int dy = c >> 1, dx = c & 1;
    int cy = y0 + dy, cx = x0 + dx;
    float wgt = (dy ? fy : 1.f - fy) * (dx ? fx : 1.f - fx);
    bool valid = (cy >= 0) & (cy < sw) & (cx >= 0) & (cx < sw);
    wgt = valid ? wgt : 0.f;
    int ccy = min(max(cy, 0), sw - 1);
    int ccx = min(max(cx, 0), sw - 1);
    w[c] = wgt * aw;
    a[c] = base_bh + (ccy * sw + ccx) * (NH_ * DH_);
  }

  // gather: 2 samples per iter (lane>>5), 32 dh lanes each
  int half = lane >> 5;
  int dh = lane & 31;
  float acc = 0.f;
#pragma unroll
  for (int i = 0; i < 8; ++i) {
    int ss = i * 2 + half;
#pragma unroll
    for (int c = 0; c < 4; ++c) {
      float wc = __shfl(w[c], ss);
      int ac = __shfl(a[c], ss);
      float g = bf2f(value[ac + dh]);
      acc = fmaf(wc, g, acc);
    }
  }
  acc += __shfl_xor(acc, 32);
  if (lane < 32) attn_feat[(size_t)bq * NC + h * DH_ + dh] = acc;
}

// ---------------- residual + LayerNorm (delta in bf16) ----------------
__global__ __launch_bounds__(256)
void ln_k(const float* __restrict__ xres, const unsigned short* __restrict__ delta,
          const float* __restrict__ g, const float* __restrict__ bta,
          float* __restrict__ out) {
  int row = blockIdx.x * 4 + (threadIdx.x >> 6);
  int lane = threadIdx.x & 63;
  size_t base = (size_t)row * NC + lane * 4;
  bf16x4 dv = *(const bf16x4*)(delta + base);
  f32x4 xv = *(const f32x4*)(xres + base);
  xv[0] += bf2f((unsigned short)dv[0]);
  xv[1] += bf2f((unsigned short)dv[1]);
  xv[2] += bf2f((unsigned short)dv[2]);
  xv[3] += bf2f((unsigned short)dv[3]);
  float ssum = xv[0] + xv[1] + xv[2] + xv[3];
#pragma unroll
  for (int o = 1; o <= 32; o <<= 1) ssum += __shfl_xor(ssum, o);
  float mean = ssum * (1.0f / NC);
  f32x4 cv = xv - mean;
  float s2 = cv[0] * cv[0] + cv[1] * cv[1] + cv[2] * cv[2] + cv[3] * cv[3];
#pragma unroll
  for (int o = 1; o <= 32; o <<= 1) s2 += __shfl_xor(s2, o);
  float rstd = rsqrtf(s2 * (1.0f / NC) + 1e-5f);
  f32x4 gv = *(const f32x4*)(g + lane * 4);
  f32x4 bv = *(const f32x4*)(bta + lane * 4);
  f32x4 ov = cv * rstd * gv + bv;
  *(f32x4*)(out + base) = ov;
}

// ---------------- launcher ----------------
extern "C" void kernel_launch(void* const* d_in, const int* in_sizes, int n_in,
                              void* d_out, int out_size, void* d_ws, size_t ws_size,
                              hipStream_t stream) {
  const float* src      = (const float*)d_in[0];
  const float* pos_flat = (const float*)d_in[1];
  const float* lvl_emb  = (const float*)d_in[2];
  const float* W_samp   = (const float*)d_in[3];
  const float* b_samp   = (const float*)d_in[4];
  const float* W_attn   = (const float*)d_in[5];
  const float* b_attn   = (const float*)d_in[6];
  const float* W_val    = (const float*)d_in[7];
  const float* b_val    = (const float*)d_in[8];
  const float* W_out    = (const float*)d_in[9];
  const float* b_out    = (const float*)d_in[10];
  const float* g1       = (const float*)d_in[11];
  const float* b1       = (const float*)d_in[12];
  const float* W_fc1    = (const float*)d_in[13];
  const float* b_fc1    = (const float*)d_in[14];
  const float* W_fc2    = (const float*)d_in[15];
  const float* b_fc2    = (const float*)d_in[16];
  const float* g2       = (const float*)d_in[17];
  const float* b2       = (const float*)d_in[18];

  char* ws = (char*)d_ws;
  size_t o = 0;
  auto alloc = [&](size_t bytes) {
    void* p = ws + o;
    o += (bytes + 255) & ~(size_t)255;
    return p;
  };
  // bb: value (M*256 bf16) / hid chunk (MCH*1024 bf16) — disjoint liveness
  unsigned short* bb    = (unsigned short*)alloc((size_t)M_ * NC * 2);
  // sa: offsets+logits (M*384 bf16); reused as y / y2 (M*256 bf16)
  unsigned short* sa    = (unsigned short*)alloc((size_t)M_ * 384 * 2);
  float* af             = (float*)alloc((size_t)M_ * NC * 4);   // attn_feat / x_mid
  float* xA             = (float*)alloc((size_t)M_ * NC * 4);
  unsigned short* Wv_t  = (unsigned short*)alloc((size_t)6 * 256 * 256 * 2);
  unsigned short* Wsa_t = (unsigned short*)alloc((size_t)6 * 384 * 256 * 2);
  unsigned short* Wo_t  = (unsigned short*)alloc((size_t)6 * 256 * 256 * 2);
  unsigned short* Wf1_t = (unsigned short*)alloc((size_t)6 * 1024 * 256 * 2);
  unsigned short* Wf2_t = (unsigned short*)alloc((size_t)6 * 256 * 1024 * 2);
  float* bsa            = (float*)alloc((size_t)6 * 384 * 4);

  // prep
  transpose_w2_k<<<1536, 256, 0, stream>>>(W_val, Wv_t, 6, 256, 256, 256, 0);
  transpose_w2_k<<<1536, 256, 0, stream>>>(W_samp, Wsa_t, 6, 256, 256, 384, 0);
  transpose_w2_k<<<768, 256, 0, stream>>>(W_attn, Wsa_t, 6, 256, 128, 384, 256);
  transpose_w2_k<<<1536, 256, 0, stream>>>(W_out, Wo_t, 6, 256, 256, 256, 0);
  transpose_w2_k<<<3072, 256, 0, stream>>>(W_fc1, Wf1_t, 6, 256, 1024, 1024, 0);
  transpose_w2_k<<<3072, 256, 0, stream>>>(W_fc2, Wf2_t, 6, 1024, 256, 256, 0);
  bias_cat_k<<<9, 256, 0, stream>>>(b_samp, b_attn, bsa);

  const float* xin = src;
  for (int i = 0; i < NLAYERS_; ++i) {
    float* xout = (i & 1) ? (float*)d_out : xA;
    // value = xin @ Wv + bv  (bf16 out)
    gemm_k<false, false, false, true><<<dim3(4, M_ / 64), 256, 0, stream>>>(
        xin, nullptr, nullptr, Wv_t + (size_t)i * 65536, b_val + i * 256, bb, 256, 256);
    // sa = (xin + pos_flat + lvl_emb) @ [Ws|Wa] + [bs|ba]  (bf16 out)
    gemm_k<false, true, false, true><<<dim3(6, M_ / 64), 256, 0, stream>>>(
        xin, pos_flat, lvl_emb, Wsa_t + (size_t)i * 98304, bsa + i * 384, sa, 256, 384);
    // deformable sampling -> af
    samp_k<<<(NB * Q_ * NH_) / 4, 256, 0, stream>>>(bb, sa, af);
    // attn proj: y = af @ Wo + bo  (bf16, into sa buffer, stride 256)
    gemm_k<false, false, false, true><<<dim3(4, M_ / 64), 256, 0, stream>>>(
        af, nullptr, nullptr, Wo_t + (size_t)i * 65536, b_out + i * 256, sa, 256, 256);
    // x_mid = LN(xin + y) -> af
    ln_k<<<M_ / 4, 256, 0, stream>>>(xin, sa, g1 + i * 256, b1 + i * 256, af);
    // FFN in 4 chunks over M (hid shares bb)
    for (int c = 0; c < 4; ++c) {
      gemm_k<false, false, true, true><<<dim3(16, MCH / 64), 256, 0, stream>>>(
          af + (size_t)c * MCH * NC, nullptr, nullptr,
          Wf1_t + (size_t)i * 262144, b_fc1 + i * 1024, bb, 256, 1024);
      gemm_k<true, false, false, true><<<dim3(4, MCH / 64), 256, 0, stream>>>(
          bb, nullptr, nullptr,
          Wf2_t + (size_t)i * 262144, b_fc2 + i * 256,
          sa + (size_t)c * MCH * NC, 1024, 256);
    }
    // out = LN(x_mid + y2)
    ln_k<<<M_ / 4, 256, 0, stream>>>(af, sa, g2 + i * 256, b2 + i * 256, xout);
    xin = xout;
  }
}

// Round 3
// 2843.711 us; speedup vs baseline: 1.2926x; 1.2926x over previous
//
#include <hip/hip_runtime.h>
#include <hip/hip_bf16.h>

#define NB 8
#define NC 256
#define NH_ 8
#define NL_ 4
#define NP_ 4
#define NLAYERS_ 6
#define FFN_ 1024
#define Q_ 5440
#define DH_ 32
#define M_ (NB*Q_)        // 43520
#define MCH (M_/4)        // 10880  (FFN chunk rows)

typedef __attribute__((ext_vector_type(8))) short bf16x8;
typedef __attribute__((ext_vector_type(4))) short bf16x4;
typedef __attribute__((ext_vector_type(4))) float f32x4;

__device__ __forceinline__ unsigned short f2bf(float f) {
  unsigned int u = __float_as_uint(f);
  u += 0x7fffu + ((u >> 16) & 1u);
  return (unsigned short)(u >> 16);
}
__device__ __forceinline__ float bf2f(unsigned short s) {
  return __uint_as_float(((unsigned int)s) << 16);
}

// ---------------- prep kernels ----------------
// W: [L][Kd][Nd] fp32  ->  Wt rows at [l][nOff+n][k] within [L][NdTot][Kd] bf16
__global__ void transpose_w2_k(const float* __restrict__ W, unsigned short* __restrict__ Wt,
                               int L, int Kd, int Nd, int NdTot, int nOff) {
  size_t total = (size_t)L * Nd * Kd;
  for (size_t i = (size_t)blockIdx.x * blockDim.x + threadIdx.x; i < total;
       i += (size_t)gridDim.x * blockDim.x) {
    int k = (int)(i % Kd);
    size_t r = i / Kd;
    int n = (int)(r % Nd);
    int l = (int)(r / Nd);
    Wt[((size_t)l * NdTot + nOff + n) * Kd + k] = f2bf(W[((size_t)l * Kd + k) * Nd + n]);
  }
}

__global__ void bias_cat_k(const float* __restrict__ bs, const float* __restrict__ ba,
                           float* __restrict__ bsa) {
  int i = blockIdx.x * blockDim.x + threadIdx.x;
  if (i >= NLAYERS_ * 384) return;
  int l = i / 384, n = i % 384;
  bsa[i] = (n < 256) ? bs[l * 256 + n] : ba[l * 128 + (n - 256)];
}

// ---------------- GEMM: Y[M,N] = X[M,K] @ Wt[N,K]^T + bias ----------------
// 128x128 tile, BK=32, 4 waves (2x2), each wave 64x64 = 4x4 frags of 16x16x32
#define LDSS 40  // LDS row stride in shorts: 32 cols + 8 pad

template <bool IN_BF16, bool ADD_POS, bool RELU, bool OUT_BF16>
__global__ __launch_bounds__(256)
void gemm_k(const void* __restrict__ Xv, const float* __restrict__ Pf,
            const float* __restrict__ Le,
            const unsigned short* __restrict__ Wt, const float* __restrict__ bias,
            void* __restrict__ Yv, int Kdim, int Ndim) {
  __shared__ unsigned short Alds[128 * LDSS];
  __shared__ unsigned short Blds[128 * LDSS];
  const int t = threadIdx.x;
  const int n0 = blockIdx.x * 128;
  const int m0 = blockIdx.y * 128;
  const int wave = t >> 6, lane = t & 63;
  const int wr = wave >> 1, wc = wave & 1;
  const int lr = lane & 15, lk = lane >> 4;
  const int sr = t >> 1, sh = (t & 1) * 16;  // staging: 128 rows x 2 half-rows of 16

  f32x4 acc[4][4];
#pragma unroll
  for (int i = 0; i < 4; ++i)
#pragma unroll
    for (int j = 0; j < 4; ++j)
#pragma unroll
      for (int e = 0; e < 4; ++e) acc[i][j][e] = 0.f;

  const float* Xf = (const float*)Xv;
  const unsigned short* Xb = (const unsigned short*)Xv;

  for (int kt = 0; kt < Kdim; kt += 32) {
    // --- stage A (fp32->bf16 convert, optional pos+level-embed add) ---
    if constexpr (!IN_BF16) {
      size_t gof = (size_t)(m0 + sr) * Kdim + kt + sh;
      f32x4 v[4];
#pragma unroll
      for (int j = 0; j < 4; ++j) v[j] = *(const f32x4*)(Xf + gof + j * 4);
      if constexpr (ADD_POS) {
        int q = (m0 + sr) % Q_;
        int lvl = q < 4096 ? 0 : (q < 5120 ? 1 : (q < 5376 ? 2 : 3));
        const float* le = Le + lvl * NC + kt + sh;
#pragma unroll
        for (int j = 0; j < 4; ++j) {
          f32x4 pv = *(const f32x4*)(Pf + gof + j * 4);
          f32x4 ev = *(const f32x4*)(le + j * 4);
          v[j] = v[j] + pv + ev;
        }
      }
#pragma unroll
      for (int j = 0; j < 4; ++j) {
        bf16x4 sv;
        sv[0] = (short)f2bf(v[j][0]); sv[1] = (short)f2bf(v[j][1]);
        sv[2] = (short)f2bf(v[j][2]); sv[3] = (short)f2bf(v[j][3]);
        *(bf16x4*)&Alds[sr * LDSS + sh + j * 4] = sv;
      }
    } else {
      size_t gof = (size_t)(m0 + sr) * Kdim + kt + sh;
      *(bf16x8*)&Alds[sr * LDSS + sh] = *(const bf16x8*)(Xb + gof);
      *(bf16x8*)&Alds[sr * LDSS + sh + 8] = *(const bf16x8*)(Xb + gof + 8);
    }
    // --- stage B from Wt[N][K] bf16 ---
    {
      size_t wof = (size_t)(n0 + sr) * Kdim + kt + sh;
      *(bf16x8*)&Blds[sr * LDSS + sh] = *(const bf16x8*)(Wt + wof);
      *(bf16x8*)&Blds[sr * LDSS + sh + 8] = *(const bf16x8*)(Wt + wof + 8);
    }
    __syncthreads();

    bf16x8 af[4], bf[4];
#pragma unroll
    for (int fi = 0; fi < 4; ++fi)
      af[fi] = *(const bf16x8*)&Alds[(wr * 64 + fi * 16 + lr) * LDSS + lk * 8];
#pragma unroll
    for (int fj = 0; fj < 4; ++fj)
      bf[fj] = *(const bf16x8*)&Blds[(wc * 64 + fj * 16 + lr) * LDSS + lk * 8];
#pragma unroll
    for (int fi = 0; fi < 4; ++fi)
#pragma unroll
      for (int fj = 0; fj < 4; ++fj)
        acc[fi][fj] = __builtin_amdgcn_mfma_f32_16x16x32_bf16(af[fi], bf[fj], acc[fi][fj], 0, 0, 0);
    __syncthreads();
  }

  // epilogue: C/D layout col=lane&15, row=(lane>>4)*4+reg  [HW-verified]
  const int orow = m0 + wr * 64;
  const int ocol = n0 + wc * 64;
#pragma unroll
  for (int fi = 0; fi < 4; ++fi)
#pragma unroll
    for (int fj = 0; fj < 4; ++fj) {
      int col = ocol + fj * 16 + lr;
      float bv = bias[col];
#pragma unroll
      for (int rr = 0; rr < 4; ++rr) {
        int row = orow + fi * 16 + lk * 4 + rr;
        float v = acc[fi][fj][rr] + bv;
        if constexpr (RELU) v = fmaxf(v, 0.f);
        if constexpr (OUT_BF16)
          ((unsigned short*)Yv)[(size_t)row * Ndim + col] = f2bf(v);
        else
          ((float*)Yv)[(size_t)row * Ndim + col] = v;
      }
    }
}

// ---------------- deformable sampling (shfl-free, vectorized) ----------------
// one wave per (b,q,h). lane = quad*16 + s: s=sample (0..15), quad=8-wide dh chunk.
// sa row (bf16, stride 384): [0..255]=offsets (h*32+s*2+{x,y}), [256..383]=logits.
__global__ __launch_bounds__(256)
void samp_k(const unsigned short* __restrict__ value, const unsigned short* __restrict__ sa,
            float* __restrict__ attn_feat) {
  int gw = blockIdx.x * 4 + (threadIdx.x >> 6);
  int lane = threadIdx.x & 63;
  int h = gw & 7;
  int bq = gw >> 3;  // 0..43519
  int q = bq % Q_;
  int b = bq / Q_;
  int s = lane & 15;
  int quad = lane >> 4;

  int lvl = q < 4096 ? 0 : (q < 5120 ? 1 : (q < 5376 ? 2 : 3));
  int qrem = q - (lvl == 0 ? 0 : lvl == 1 ? 4096 : lvl == 2 ? 5120 : 5376);
  int wlog = 6 - lvl;
  float inv = __uint_as_float((unsigned)(127 - wlog) << 23);  // 1/2^wlog
  float refx = ((qrem & ((1 << wlog) - 1)) + 0.5f) * inv;
  float refy = ((qrem >> wlog) + 0.5f) * inv;

  const unsigned short* sa_bq = sa + (size_t)bq * 384;

  // softmax over 16 samples (per-lane own logit, xor-reduce within 16-group)
  float logit = bf2f(sa_bq[256 + h * 16 + s]);
  float mx = fmaxf(logit, __shfl_xor(logit, 1));
  mx = fmaxf(mx, __shfl_xor(mx, 2));
  mx = fmaxf(mx, __shfl_xor(mx, 4));
  mx = fmaxf(mx, __shfl_xor(mx, 8));
  float e = __expf(logit - mx);
  float sum = e;
  sum += __shfl_xor(sum, 1);
  sum += __shfl_xor(sum, 2);
  sum += __shfl_xor(sum, 4);
  sum += __shfl_xor(sum, 8);
  float aw = e / sum;

  // per-sample bilinear setup (s = lane&15; replicated across quads)
  float ox = bf2f(sa_bq[h * 32 + s * 2 + 0]);
  float oy = bf2f(sa_bq[h * 32 + s * 2 + 1]);
  int sl = s >> 2;
  int swlog = 6 - sl;
  int sw = 1 << swlog;
  int sstart = (sl == 0) ? 0 : (sl == 1) ? 4096 : (sl == 2) ? 5120 : 5376;
  float x = fmaf(refx, (float)sw, ox) - 0.5f;
  float y = fmaf(refy, (float)sw, oy) - 0.5f;
  float x0f = floorf(x), y0f = floorf(y);
  float fx = x - x0f, fy = y - y0f;
  int x0 = (int)x0f, y0 = (int)y0f;
  float w[4];
  int a[4];
  int base_bh = ((b * Q_ + sstart) * NH_ + h) * DH_ + quad * 8;
#pragma unroll
  for (int c = 0; c < 4; ++c) {
    int dy = c >> 1, dx = c & 1;
    int cy = y0 + dy, cx = x0 + dx;
    float wgt = (dy ? fy : 1.f - fy) * (dx ? fx : 1.f - fx);
    bool valid = (cy >= 0) & (cy < sw) & (cx >= 0) & (cx < sw);
    wgt = valid ? wgt : 0.f;
    int ccy = min(max(cy, 0), sw - 1);
    int ccx = min(max(cx, 0), sw - 1);
    w[c] = wgt * aw;
    a[c] = base_bh + (ccy * sw + ccx) * (NH_ * DH_);
  }

  // gather: each lane loads 8 dh (16B) per corner for its own sample
  float acc0 = 0.f, acc1 = 0.f, acc2 = 0.f, acc3 = 0.f;
  float acc4 = 0.f, acc5 = 0.f, acc6 = 0.f, acc7 = 0.f;
#pragma unroll
  for (int c = 0; c < 4; ++c) {
    bf16x8 g = *(const bf16x8*)(value + a[c]);
    float wc = w[c];
    acc0 = fmaf(wc, bf2f((unsigned short)g[0]), acc0);
    acc1 = fmaf(wc, bf2f((unsigned short)g[1]), acc1);
    acc2 = fmaf(wc, bf2f((unsigned short)g[2]), acc2);
    acc3 = fmaf(wc, bf2f((unsigned short)g[3]), acc3);
    acc4 = fmaf(wc, bf2f((unsigned short)g[4]), acc4);
    acc5 = fmaf(wc, bf2f((unsigned short)g[5]), acc5);
    acc6 = fmaf(wc, bf2f((unsigned short)g[6]), acc6);
    acc7 = fmaf(wc, bf2f((unsigned short)g[7]), acc7);
  }
  // reduce over the 16 samples (xor within 16-lane group; quad preserved)
#pragma unroll
  for (int o = 1; o <= 8; o <<= 1) {
    acc0 += __shfl_xor(acc0, o);
    acc1 += __shfl_xor(acc1, o);
    acc2 += __shfl_xor(acc2, o);
    acc3 += __shfl_xor(acc3, o);
    acc4 += __shfl_xor(acc4, o);
    acc5 += __shfl_xor(acc5, o);
    acc6 += __shfl_xor(acc6, o);
    acc7 += __shfl_xor(acc7, o);
  }
  if (s == 0) {
    float* op = attn_feat + (size_t)bq * NC + h * DH_ + quad * 8;
    f32x4 lo, hi;
    lo[0] = acc0; lo[1] = acc1; lo[2] = acc2; lo[3] = acc3;
    hi[0] = acc4; hi[1] = acc5; hi[2] = acc6; hi[3] = acc7;
    *(f32x4*)op = lo;
    *(f32x4*)(op + 4) = hi;
  }
}

// ---------------- residual + LayerNorm (delta in bf16) ----------------
__global__ __launch_bounds__(256)
void ln_k(const float* __restrict__ xres, const unsigned short* __restrict__ delta,
          const float* __restrict__ g, const float* __restrict__ bta,
          float* __restrict__ out) {
  int row = blockIdx.x * 4 + (threadIdx.x >> 6);
  int lane = threadIdx.x & 63;
  size_t base = (size_t)row * NC + lane * 4;
  bf16x4 dv = *(const bf16x4*)(delta + base);
  f32x4 xv = *(const f32x4*)(xres + base);
  xv[0] += bf2f((unsigned short)dv[0]);
  xv[1] += bf2f((unsigned short)dv[1]);
  xv[2] += bf2f((unsigned short)dv[2]);
  xv[3] += bf2f((unsigned short)dv[3]);
  float ssum = xv[0] + xv[1] + xv[2] + xv[3];
#pragma unroll
  for (int o = 1; o <= 32; o <<= 1) ssum += __shfl_xor(ssum, o);
  float mean = ssum * (1.0f / NC);
  f32x4 cv = xv - mean;
  float s2 = cv[0] * cv[0] + cv[1] * cv[1] + cv[2] * cv[2] + cv[3] * cv[3];
#pragma unroll
  for (int o = 1; o <= 32; o <<= 1) s2 += __shfl_xor(s2, o);
  float rstd = rsqrtf(s2 * (1.0f / NC) + 1e-5f);
  f32x4 gv = *(const f32x4*)(g + lane * 4);
  f32x4 bv = *(const f32x4*)(bta + lane * 4);
  f32x4 ov = cv * rstd * gv + bv;
  *(f32x4*)(out + base) = ov;
}

// ---------------- launcher ----------------
extern "C" void kernel_launch(void* const* d_in, const int* in_sizes, int n_in,
                              void* d_out, int out_size, void* d_ws, size_t ws_size,
                              hipStream_t stream) {
  const float* src      = (const float*)d_in[0];
  const float* pos_flat = (const float*)d_in[1];
  const float* lvl_emb  = (const float*)d_in[2];
  const float* W_samp   = (const float*)d_in[3];
  const float* b_samp   = (const float*)d_in[4];
  const float* W_attn   = (const float*)d_in[5];
  const float* b_attn   = (const float*)d_in[6];
  const float* W_val    = (const float*)d_in[7];
  const float* b_val    = (const float*)d_in[8];
  const float* W_out    = (const float*)d_in[9];
  const float* b_out    = (const float*)d_in[10];
  const float* g1       = (const float*)d_in[11];
  const float* b1       = (const float*)d_in[12];
  const float* W_fc1    = (const float*)d_in[13];
  const float* b_fc1    = (const float*)d_in[14];
  const float* W_fc2    = (const float*)d_in[15];
  const float* b_fc2    = (const float*)d_in[16];
  const float* g2       = (const float*)d_in[17];
  const float* b2       = (const float*)d_in[18];

  char* ws = (char*)d_ws;
  size_t o = 0;
  auto alloc = [&](size_t bytes) {
    void* p = ws + o;
    o += (bytes + 255) & ~(size_t)255;
    return p;
  };
  // bb: value (M*256 bf16) / hid chunk (MCH*1024 bf16) — disjoint liveness
  unsigned short* bb    = (unsigned short*)alloc((size_t)M_ * NC * 2);
  // sa: offsets+logits (M*384 bf16); reused as y / y2 (M*256 bf16)
  unsigned short* sa    = (unsigned short*)alloc((size_t)M_ * 384 * 2);
  float* af             = (float*)alloc((size_t)M_ * NC * 4);   // attn_feat / x_mid
  float* xA             = (float*)alloc((size_t)M_ * NC * 4);
  unsigned short* Wv_t  = (unsigned short*)alloc((size_t)6 * 256 * 256 * 2);
  unsigned short* Wsa_t = (unsigned short*)alloc((size_t)6 * 384 * 256 * 2);
  unsigned short* Wo_t  = (unsigned short*)alloc((size_t)6 * 256 * 256 * 2);
  unsigned short* Wf1_t = (unsigned short*)alloc((size_t)6 * 1024 * 256 * 2);
  unsigned short* Wf2_t = (unsigned short*)alloc((size_t)6 * 256 * 1024 * 2);
  float* bsa            = (float*)alloc((size_t)6 * 384 * 4);

  // prep
  transpose_w2_k<<<1536, 256, 0, stream>>>(W_val, Wv_t, 6, 256, 256, 256, 0);
  transpose_w2_k<<<1536, 256, 0, stream>>>(W_samp, Wsa_t, 6, 256, 256, 384, 0);
  transpose_w2_k<<<768, 256, 0, stream>>>(W_attn, Wsa_t, 6, 256, 128, 384, 256);
  transpose_w2_k<<<1536, 256, 0, stream>>>(W_out, Wo_t, 6, 256, 256, 256, 0);
  transpose_w2_k<<<3072, 256, 0, stream>>>(W_fc1, Wf1_t, 6, 256, 1024, 1024, 0);
  transpose_w2_k<<<3072, 256, 0, stream>>>(W_fc2, Wf2_t, 6, 1024, 256, 256, 0);
  bias_cat_k<<<9, 256, 0, stream>>>(b_samp, b_attn, bsa);

  const float* xin = src;
  for (int i = 0; i < NLAYERS_; ++i) {
    float* xout = (i & 1) ? (float*)d_out : xA;
    // value = xin @ Wv + bv  (bf16 out)
    gemm_k<false, false, false, true><<<dim3(2, M_ / 128), 256, 0, stream>>>(
        xin, nullptr, nullptr, Wv_t + (size_t)i * 65536, b_val + i * 256, bb, 256, 256);
    // sa = (xin + pos_flat + lvl_emb) @ [Ws|Wa] + [bs|ba]  (bf16 out)
    gemm_k<false, true, false, true><<<dim3(3, M_ / 128), 256, 0, stream>>>(
        xin, pos_flat, lvl_emb, Wsa_t + (size_t)i * 98304, bsa + i * 384, sa, 256, 384);
    // deformable sampling -> af
    samp_k<<<(NB * Q_ * NH_) / 4, 256, 0, stream>>>(bb, sa, af);
    // attn proj: y = af @ Wo + bo  (bf16, into sa buffer, stride 256)
    gemm_k<false, false, false, true><<<dim3(2, M_ / 128), 256, 0, stream>>>(
        af, nullptr, nullptr, Wo_t + (size_t)i * 65536, b_out + i * 256, sa, 256, 256);
    // x_mid = LN(xin + y) -> af
    ln_k<<<M_ / 4, 256, 0, stream>>>(xin, sa, g1 + i * 256, b1 + i * 256, af);
    // FFN in 4 chunks over M (hid shares bb)
    for (int c = 0; c < 4; ++c) {
      gemm_k<false, false, true, true><<<dim3(8, MCH / 128), 256, 0, stream>>>(
          af + (size_t)c * MCH * NC, nullptr, nullptr,
          Wf1_t + (size_t)i * 262144, b_fc1 + i * 1024, bb, 256, 1024);
      gemm_k<true, false, false, true><<<dim3(2, MCH / 128), 256, 0, stream>>>(
          bb, nullptr, nullptr,
          Wf2_t + (size_t)i * 262144, b_fc2 + i * 256,
          sa + (size_t)c * MCH * NC, 1024, 256);
    }
    // out = LN(x_mid + y2)
    ln_k<<<M_ / 4, 256, 0, stream>>>(af, sa, g2 + i * 256, b2 + i * 256, xout);
    xin = xout;
  }
}

// Round 4
// 2047.827 us; speedup vs baseline: 1.7949x; 1.3886x over previous
//
#include <hip/hip_runtime.h>
#include <hip/hip_bf16.h>

#define NB 8
#define NC 256
#define NH_ 8
#define NLAYERS_ 6
#define FFN_ 1024
#define Q_ 5440
#define DH_ 32
#define M_ (NB*Q_)        // 43520
#define MCH (M_/4)        // 10880  (FFN chunk rows)

typedef __attribute__((ext_vector_type(8))) short bf16x8;
typedef __attribute__((ext_vector_type(4))) short bf16x4;
typedef __attribute__((ext_vector_type(4))) float f32x4;
typedef __attribute__((ext_vector_type(4))) int i32x4;
typedef unsigned int u32;

__device__ __forceinline__ unsigned short f2bf(float f) {
  unsigned int u = __float_as_uint(f);
  u += 0x7fffu + ((u >> 16) & 1u);
  return (unsigned short)(u >> 16);
}
__device__ __forceinline__ float bf2f(unsigned short s) {
  return __uint_as_float(((unsigned int)s) << 16);
}
__device__ __forceinline__ void gl16(const unsigned short* g, unsigned short* l) {
  __builtin_amdgcn_global_load_lds((const __attribute__((address_space(1))) u32*)(g),
                                   (__attribute__((address_space(3))) u32*)(l), 16, 0, 0);
}

// ---------------- prep kernels ----------------
// W: [L][Kd][Nd] fp32  ->  Wt rows at [l][nOff+n][k] within [L][NdTot][Kd] bf16
__global__ void transpose_w2_k(const float* __restrict__ W, unsigned short* __restrict__ Wt,
                               int L, int Kd, int Nd, int NdTot, int nOff) {
  size_t total = (size_t)L * Nd * Kd;
  for (size_t i = (size_t)blockIdx.x * blockDim.x + threadIdx.x; i < total;
       i += (size_t)gridDim.x * blockDim.x) {
    int k = (int)(i % Kd);
    size_t r = i / Kd;
    int n = (int)(r % Nd);
    int l = (int)(r / Nd);
    Wt[((size_t)l * NdTot + nOff + n) * Kd + k] = f2bf(W[((size_t)l * Kd + k) * Nd + n]);
  }
}

__global__ void bias_cat_k(const float* __restrict__ bs, const float* __restrict__ ba,
                           float* __restrict__ bsa) {
  int i = blockIdx.x * blockDim.x + threadIdx.x;
  if (i >= NLAYERS_ * 384) return;
  int l = i / 384, n = i % 384;
  bsa[i] = (n < 256) ? bs[l * 256 + n] : ba[l * 128 + (n - 256)];
}

// layer-0: xb = bf16(src), qb = bf16(src + pos + lvl_emb)
__global__ __launch_bounds__(256)
void pre_k(const float* __restrict__ src, const float* __restrict__ pf,
           const float* __restrict__ le,
           unsigned short* __restrict__ xb, unsigned short* __restrict__ qb) {
  int row = blockIdx.x * 4 + (threadIdx.x >> 6);
  int lane = threadIdx.x & 63;
  size_t base = (size_t)row * NC + lane * 4;
  int q = row % Q_;
  int lvl = q < 4096 ? 0 : (q < 5120 ? 1 : (q < 5376 ? 2 : 3));
  f32x4 xv = *(const f32x4*)(src + base);
  f32x4 qv = xv + *(const f32x4*)(pf + base) + *(const f32x4*)(le + lvl * NC + lane * 4);
  bf16x4 xo, qo;
#pragma unroll
  for (int j = 0; j < 4; ++j) { xo[j] = (short)f2bf(xv[j]); qo[j] = (short)f2bf(qv[j]); }
  *(bf16x4*)(xb + base) = xo;
  *(bf16x4*)(qb + base) = qo;
}

// ---------------- GEMM: Y[M,N] = X[M,K] @ Wt[N,K]^T + bias (bf16 in/out) ----
// 128x128 tile, BK=32, 4 waves (2x2), each wave 64x64 = 4x4 frags of 16x16x32.
// LDS linear (gload_lds dest); swizzle via pre-swizzled GLOBAL src + swizzled read.
__device__ __forceinline__ int swz(int r, int sl) { return sl ^ (r & 3) ^ ((r >> 2) & 3); }

template <bool RELU>
__global__ __launch_bounds__(256)
void gemm_k(const unsigned short* __restrict__ X, const unsigned short* __restrict__ Wt,
            const float* __restrict__ bias, unsigned short* __restrict__ Y,
            int Kdim, int Ndim) {
  __shared__ unsigned short Alds[128 * 32];
  __shared__ unsigned short Blds[128 * 32];
  const int t = threadIdx.x;
  const int n0 = blockIdx.x * 128;
  const int m0 = blockIdx.y * 128;
  const int wave = t >> 6, lane = t & 63;
  const int wr = wave >> 1, wc = wave & 1;
  const int lr = lane & 15, lk = lane >> 4;

  f32x4 acc[4][4];
#pragma unroll
  for (int i = 0; i < 4; ++i)
#pragma unroll
    for (int j = 0; j < 4; ++j)
#pragma unroll
      for (int e = 0; e < 4; ++e) acc[i][j][e] = 0.f;

  // staging map (per call c): idx = c*256+t; LDS slot idx holds (row idx>>2,
  // global 16B-slot gs = (idx&3) ^ m(row)) — involution with the read swizzle.
  const int r0 = t >> 2, sl0 = t & 3;
  const int r1 = (256 + t) >> 2;

  for (int kt = 0; kt < Kdim; kt += 32) {
    {
      int gs0 = swz(r0, sl0);
      gl16(X + (size_t)(m0 + r0) * Kdim + kt + gs0 * 8, Alds + (size_t)t * 8);
      gl16(Wt + (size_t)(n0 + r0) * Kdim + kt + gs0 * 8, Blds + (size_t)t * 8);
      int gs1 = swz(r1, sl0);
      gl16(X + (size_t)(m0 + r1) * Kdim + kt + gs1 * 8, Alds + (size_t)(256 + t) * 8);
      gl16(Wt + (size_t)(n0 + r1) * Kdim + kt + gs1 * 8, Blds + (size_t)(256 + t) * 8);
    }
    __syncthreads();

    bf16x8 ar[4], br[4];
#pragma unroll
    for (int fi = 0; fi < 4; ++fi) {
      int r = wr * 64 + fi * 16 + lr;
      ar[fi] = *(const bf16x8*)&Alds[r * 32 + swz(r, lk) * 8];
    }
#pragma unroll
    for (int fj = 0; fj < 4; ++fj) {
      int r = wc * 64 + fj * 16 + lr;
      br[fj] = *(const bf16x8*)&Blds[r * 32 + swz(r, lk) * 8];
    }
#pragma unroll
    for (int fi = 0; fi < 4; ++fi)
#pragma unroll
      for (int fj = 0; fj < 4; ++fj)
        acc[fi][fj] = __builtin_amdgcn_mfma_f32_16x16x32_bf16(ar[fi], br[fj], acc[fi][fj], 0, 0, 0);
    __syncthreads();
  }

  // epilogue: C/D layout col=lane&15, row=(lane>>4)*4+reg  [HW-verified]
  const int orow = m0 + wr * 64;
  const int ocol = n0 + wc * 64;
#pragma unroll
  for (int fi = 0; fi < 4; ++fi)
#pragma unroll
    for (int fj = 0; fj < 4; ++fj) {
      int col = ocol + fj * 16 + lr;
      float bv = bias[col];
#pragma unroll
      for (int rr = 0; rr < 4; ++rr) {
        int row = orow + fi * 16 + lk * 4 + rr;
        float v = acc[fi][fj][rr] + bv;
        if constexpr (RELU) v = fmaxf(v, 0.f);
        Y[(size_t)row * Ndim + col] = f2bf(v);
      }
    }
}

// ---------------- deformable sampling: one wave per (b,q) ----------------
// setup: lane -> 2 (h,s) pairs, writes {w[4],a[4]} to LDS at [s*8+h].
// gather: lane=(h:3,half:1,quad:2); in-lane accumulate over 8 samples.
__global__ __launch_bounds__(256)
void samp_k(const unsigned short* __restrict__ value, const unsigned short* __restrict__ sa,
            unsigned short* __restrict__ attn_feat) {
  __shared__ float lw[4][128][4];
  __shared__ int   la[4][128][4];
  const int wid = threadIdx.x >> 6, lane = threadIdx.x & 63;
  const int bq = blockIdx.x * 4 + wid;
  const int q = bq % Q_;
  const int b = bq / Q_;

  int lvl = q < 4096 ? 0 : (q < 5120 ? 1 : (q < 5376 ? 2 : 3));
  int qrem = q - (lvl == 0 ? 0 : lvl == 1 ? 4096 : lvl == 2 ? 5120 : 5376);
  int wlog = 6 - lvl;
  float inv = __uint_as_float((unsigned)(127 - wlog) << 23);  // 1/2^wlog
  float refx = ((qrem & ((1 << wlog) - 1)) + 0.5f) * inv;
  float refy = ((qrem >> wlog) + 0.5f) * inv;
  const unsigned short* sa_bq = sa + (size_t)bq * 384;

  // ---- setup: h_s = lane>>3, samples s0, s0+1 ----
  const int h_s = lane >> 3;
  const int s0 = (lane & 7) * 2;
  unsigned lg01 = *(const unsigned*)&sa_bq[256 + h_s * 16 + s0];
  float lg0 = bf2f((unsigned short)(lg01 & 0xffff));
  float lg1 = bf2f((unsigned short)(lg01 >> 16));
  float mx = fmaxf(lg0, lg1);
  mx = fmaxf(mx, __shfl_xor(mx, 1));
  mx = fmaxf(mx, __shfl_xor(mx, 2));
  mx = fmaxf(mx, __shfl_xor(mx, 4));
  float e0 = __expf(lg0 - mx), e1 = __expf(lg1 - mx);
  float sm = e0 + e1;
  sm += __shfl_xor(sm, 1);
  sm += __shfl_xor(sm, 2);
  sm += __shfl_xor(sm, 4);
  float rs = 1.0f / sm;

#pragma unroll
  for (int j = 0; j < 2; ++j) {
    int s = s0 + j;
    float aw = (j ? e1 : e0) * rs;
    unsigned oxy = *(const unsigned*)&sa_bq[h_s * 32 + s * 2];
    float ox = bf2f((unsigned short)(oxy & 0xffff));
    float oy = bf2f((unsigned short)(oxy >> 16));
    int sl = s >> 2;
    int swl = 6 - sl;
    int sw = 1 << swl;
    int sstart = (sl == 0) ? 0 : (sl == 1) ? 4096 : (sl == 2) ? 5120 : 5376;
    float x = fmaf(refx, (float)sw, ox) - 0.5f;
    float y = fmaf(refy, (float)sw, oy) - 0.5f;
    float x0f = floorf(x), y0f = floorf(y);
    float fx = x - x0f, fy = y - y0f;
    int x0 = (int)x0f, y0 = (int)y0f;
    int rowbase = b * Q_ + sstart;
    f32x4 wv; i32x4 av;
#pragma unroll
    for (int c = 0; c < 4; ++c) {
      int dy = c >> 1, dx = c & 1;
      int cy = y0 + dy, cx = x0 + dx;
      float wgt = (dy ? fy : 1.f - fy) * (dx ? fx : 1.f - fx);
      bool valid = (cy >= 0) & (cy < sw) & (cx >= 0) & (cx < sw);
      wgt = valid ? wgt : 0.f;
      int ccy = min(max(cy, 0), sw - 1);
      int ccx = min(max(cx, 0), sw - 1);
      wv[c] = wgt * aw;
      av[c] = ((rowbase + (ccy << swl) + ccx) * NH_ + h_s) * DH_;
    }
    int idx = s * 8 + h_s;
    *(f32x4*)&lw[wid][idx][0] = wv;
    *(i32x4*)&la[wid][idx][0] = av;
  }
  __syncthreads();

  // ---- gather ----
  const int h = lane >> 3;
  const int half = (lane >> 2) & 1;
  const int quad = lane & 3;
  const unsigned short* vq = value + quad * 8;
  float a0 = 0.f, a1 = 0.f, a2 = 0.f, a3 = 0.f, a4 = 0.f, a5 = 0.f, a6 = 0.f, a7 = 0.f;
#pragma unroll
  for (int i = 0; i < 8; ++i) {
    int idx = (half * 8 + i) * 8 + h;
    f32x4 wv = *(const f32x4*)&lw[wid][idx][0];
    i32x4 av = *(const i32x4*)&la[wid][idx][0];
#pragma unroll
    for (int c = 0; c < 4; ++c) {
      bf16x8 g = *(const bf16x8*)(vq + av[c]);
      float wcc = wv[c];
      a0 = fmaf(wcc, bf2f((unsigned short)g[0]), a0);
      a1 = fmaf(wcc, bf2f((unsigned short)g[1]), a1);
      a2 = fmaf(wcc, bf2f((unsigned short)g[2]), a2);
      a3 = fmaf(wcc, bf2f((unsigned short)g[3]), a3);
      a4 = fmaf(wcc, bf2f((unsigned short)g[4]), a4);
      a5 = fmaf(wcc, bf2f((unsigned short)g[5]), a5);
      a6 = fmaf(wcc, bf2f((unsigned short)g[6]), a6);
      a7 = fmaf(wcc, bf2f((unsigned short)g[7]), a7);
    }
  }
  a0 += __shfl_xor(a0, 4); a1 += __shfl_xor(a1, 4);
  a2 += __shfl_xor(a2, 4); a3 += __shfl_xor(a3, 4);
  a4 += __shfl_xor(a4, 4); a5 += __shfl_xor(a5, 4);
  a6 += __shfl_xor(a6, 4); a7 += __shfl_xor(a7, 4);
  if (half == 0) {
    bf16x8 ov;
    ov[0] = (short)f2bf(a0); ov[1] = (short)f2bf(a1);
    ov[2] = (short)f2bf(a2); ov[3] = (short)f2bf(a3);
    ov[4] = (short)f2bf(a4); ov[5] = (short)f2bf(a5);
    ov[6] = (short)f2bf(a6); ov[7] = (short)f2bf(a7);
    *(bf16x8*)(attn_feat + (size_t)bq * NC + h * DH_ + quad * 8) = ov;
  }
}

// ---------------- LayerNorm variants ----------------
__device__ __forceinline__ f32x4 ln_core(f32x4 xv, const float* g, const float* bta, int lane) {
  float ssum = xv[0] + xv[1] + xv[2] + xv[3];
#pragma unroll
  for (int o = 1; o <= 32; o <<= 1) ssum += __shfl_xor(ssum, o);
  float mean = ssum * (1.0f / NC);
  f32x4 cv = xv - mean;
  float s2 = cv[0] * cv[0] + cv[1] * cv[1] + cv[2] * cv[2] + cv[3] * cv[3];
#pragma unroll
  for (int o = 1; o <= 32; o <<= 1) s2 += __shfl_xor(s2, o);
  float rstd = rsqrtf(s2 * (1.0f / NC) + 1e-5f);
  f32x4 gv = *(const f32x4*)(g + lane * 4);
  f32x4 bv = *(const f32x4*)(bta + lane * 4);
  return cv * rstd * gv + bv;
}

// x_mid = LN(xin + y): writes f32 (residual) + bf16 (fc1 input)
__global__ __launch_bounds__(256)
void ln_mid_k(const float* __restrict__ xres, const unsigned short* __restrict__ delta,
              const float* __restrict__ g, const float* __restrict__ bta,
              float* __restrict__ outf, unsigned short* __restrict__ outb) {
  int row = blockIdx.x * 4 + (threadIdx.x >> 6);
  int lane = threadIdx.x & 63;
  size_t base = (size_t)row * NC + lane * 4;
  bf16x4 dv = *(const bf16x4*)(delta + base);
  f32x4 xv = *(const f32x4*)(xres + base);
#pragma unroll
  for (int j = 0; j < 4; ++j) xv[j] += bf2f((unsigned short)dv[j]);
  f32x4 ov = ln_core(xv, g, bta, lane);
  *(f32x4*)(outf + base) = ov;
  bf16x4 ob;
#pragma unroll
  for (int j = 0; j < 4; ++j) ob[j] = (short)f2bf(ov[j]);
  *(bf16x4*)(outb + base) = ob;
}

// x = LN(xm + y2) (in-place safe): writes f32 + xb bf16 + qb = bf16(x+pos+lvl)
__global__ __launch_bounds__(256)
void ln_end_k(const float* __restrict__ xmf, const unsigned short* __restrict__ delta,
              const float* __restrict__ g, const float* __restrict__ bta,
              const float* __restrict__ pf, const float* __restrict__ le,
              float* __restrict__ outf, unsigned short* __restrict__ xb,
              unsigned short* __restrict__ qb) {
  int row = blockIdx.x * 4 + (threadIdx.x >> 6);
  int lane = threadIdx.x & 63;
  size_t base = (size_t)row * NC + lane * 4;
  bf16x4 dv = *(const bf16x4*)(delta + base);
  f32x4 xv = *(const f32x4*)(xmf + base);
#pragma unroll
  for (int j = 0; j < 4; ++j) xv[j] += bf2f((unsigned short)dv[j]);
  f32x4 ov = ln_core(xv, g, bta, lane);
  *(f32x4*)(outf + base) = ov;
  int q = row % Q_;
  int lvl = q < 4096 ? 0 : (q < 5120 ? 1 : (q < 5376 ? 2 : 3));
  f32x4 qv = ov + *(const f32x4*)(pf + base) + *(const f32x4*)(le + lvl * NC + lane * 4);
  bf16x4 xo, qo;
#pragma unroll
  for (int j = 0; j < 4; ++j) { xo[j] = (short)f2bf(ov[j]); qo[j] = (short)f2bf(qv[j]); }
  *(bf16x4*)(xb + base) = xo;
  *(bf16x4*)(qb + base) = qo;
}

// ---------------- launcher ----------------
extern "C" void kernel_launch(void* const* d_in, const int* in_sizes, int n_in,
                              void* d_out, int out_size, void* d_ws, size_t ws_size,
                              hipStream_t stream) {
  const float* src      = (const float*)d_in[0];
  const float* pos_flat = (const float*)d_in[1];
  const float* lvl_emb  = (const float*)d_in[2];
  const float* W_samp   = (const float*)d_in[3];
  const float* b_samp   = (const float*)d_in[4];
  const float* W_attn   = (const float*)d_in[5];
  const float* b_attn   = (const float*)d_in[6];
  const float* W_val    = (const float*)d_in[7];
  const float* b_val    = (const float*)d_in[8];
  const float* W_out    = (const float*)d_in[9];
  const float* b_out    = (const float*)d_in[10];
  const float* g1       = (const float*)d_in[11];
  const float* b1       = (const float*)d_in[12];
  const float* W_fc1    = (const float*)d_in[13];
  const float* b_fc1    = (const float*)d_in[14];
  const float* W_fc2    = (const float*)d_in[15];
  const float* b_fc2    = (const float*)d_in[16];
  const float* g2       = (const float*)d_in[17];
  const float* b2       = (const float*)d_in[18];

  char* ws = (char*)d_ws;
  size_t o = 0;
  auto alloc = [&](size_t bytes) {
    void* p = ws + o;
    o += (bytes + 255) & ~(size_t)255;
    return p;
  };
  // bb: value (M*256 bf16) / hid chunk (MCH*1024 bf16) — disjoint liveness
  unsigned short* bb    = (unsigned short*)alloc((size_t)M_ * NC * 2);
  // sa: offsets+logits (M*384 bf16); reused as y / y2 (M*256 bf16)
  unsigned short* sa    = (unsigned short*)alloc((size_t)M_ * 384 * 2);
  unsigned short* af    = (unsigned short*)alloc((size_t)M_ * NC * 2);  // attn_feat bf16
  float* xA             = (float*)alloc((size_t)M_ * NC * 4);           // f32 x (even layers)
  unsigned short* xb    = (unsigned short*)alloc((size_t)M_ * NC * 2);  // bf16(x)
  unsigned short* qb    = (unsigned short*)alloc((size_t)M_ * NC * 2);  // bf16(x+pos) / bf16(x_mid)
  unsigned short* Wv_t  = (unsigned short*)alloc((size_t)6 * 256 * 256 * 2);
  unsigned short* Wsa_t = (unsigned short*)alloc((size_t)6 * 384 * 256 * 2);
  unsigned short* Wo_t  = (unsigned short*)alloc((size_t)6 * 256 * 256 * 2);
  unsigned short* Wf1_t = (unsigned short*)alloc((size_t)6 * 1024 * 256 * 2);
  unsigned short* Wf2_t = (unsigned short*)alloc((size_t)6 * 256 * 1024 * 2);
  float* bsa            = (float*)alloc((size_t)6 * 384 * 4);

  // prep
  transpose_w2_k<<<1536, 256, 0, stream>>>(W_val, Wv_t, 6, 256, 256, 256, 0);
  transpose_w2_k<<<1536, 256, 0, stream>>>(W_samp, Wsa_t, 6, 256, 256, 384, 0);
  transpose_w2_k<<<768, 256, 0, stream>>>(W_attn, Wsa_t, 6, 256, 128, 384, 256);
  transpose_w2_k<<<1536, 256, 0, stream>>>(W_out, Wo_t, 6, 256, 256, 256, 0);
  transpose_w2_k<<<3072, 256, 0, stream>>>(W_fc1, Wf1_t, 6, 256, 1024, 1024, 0);
  transpose_w2_k<<<3072, 256, 0, stream>>>(W_fc2, Wf2_t, 6, 1024, 256, 256, 0);
  bias_cat_k<<<9, 256, 0, stream>>>(b_samp, b_attn, bsa);
  pre_k<<<M_ / 4, 256, 0, stream>>>(src, pos_flat, lvl_emb, xb, qb);

  const float* xin = src;
  for (int i = 0; i < NLAYERS_; ++i) {
    float* xout = (i & 1) ? (float*)d_out : xA;
    // value = x @ Wv + bv
    gemm_k<false><<<dim3(2, M_ / 128), 256, 0, stream>>>(
        xb, Wv_t + (size_t)i * 65536, b_val + i * 256, bb, 256, 256);
    // sa = q @ [Ws|Wa] + [bs|ba]
    gemm_k<false><<<dim3(3, M_ / 128), 256, 0, stream>>>(
        qb, Wsa_t + (size_t)i * 98304, bsa + i * 384, sa, 256, 384);
    // deformable sampling -> af (bf16)
    samp_k<<<M_ / 4, 256, 0, stream>>>(bb, sa, af);
    // y = af @ Wo + bo (into sa, stride 256)
    gemm_k<false><<<dim3(2, M_ / 128), 256, 0, stream>>>(
        af, Wo_t + (size_t)i * 65536, b_out + i * 256, sa, 256, 256);
    // x_mid = LN(xin + y) -> xout (f32) + qb (bf16)
    ln_mid_k<<<M_ / 4, 256, 0, stream>>>(xin, sa, g1 + i * 256, b1 + i * 256, xout, qb);
    // FFN in 4 chunks over M (hid shares bb)
    for (int c = 0; c < 4; ++c) {
      gemm_k<true><<<dim3(8, MCH / 128), 256, 0, stream>>>(
          qb + (size_t)c * MCH * NC, Wf1_t + (size_t)i * 262144, b_fc1 + i * 1024, bb, 256, 1024);
      gemm_k<false><<<dim3(2, MCH / 128), 256, 0, stream>>>(
          bb, Wf2_t + (size_t)i * 262144, b_fc2 + i * 256, sa + (size_t)c * MCH * NC, 1024, 256);
    }
    // x = LN(x_mid + y2) in-place on xout; also write xb, qb for next layer
    ln_end_k<<<M_ / 4, 256, 0, stream>>>(xout, sa, g2 + i * 256, b2 + i * 256,
                                         pos_flat, lvl_emb, xout, xb, qb);
    xin = xout;
  }
}